// Round 3
// baseline (529.050 us; speedup 1.0000x reference)
//
#include <hip/hip_runtime.h>
#include <hip/hip_bf16.h>
#include <math.h>

namespace {
constexpr int Ln   = 2048;
constexpr int Kn   = 32;
constexpr int EFn  = 128;
constexpr int ROWS = 4 * Ln;                               // 8192
constexpr size_t V_ELEMS = (size_t)ROWS * EFn;             // 1048576
constexpr size_t E_ELEMS = (size_t)ROWS * Kn * EFn;        // 33554432
constexpr size_t IDX_OFF = V_ELEMS + E_ELEMS;              // 34603008
constexpr size_t T_BYTES = (size_t)7 * 66 * EFn * 4;       // 236544

__device__ __forceinline__ unsigned int orderKey(float f) {
  unsigned int u = __float_as_uint(f);
  return (u & 0x80000000u) ? ~u : (u | 0x80000000u);
}
__device__ __forceinline__ float keyToFloat(unsigned int k) {
  unsigned int u = (k & 0x80000000u) ? (k & 0x7fffffffu) : ~k;
  return __uint_as_float(u);
}
__device__ __forceinline__ unsigned long long u64min(unsigned long long a, unsigned long long b) {
  return a < b ? a : b;
}
} // namespace

// T[n][d][c] = sum_m (pos_W[d,m] + pos_b[m]) * edge_W[n*16+m, c]
__global__ void pf_tab(const float* __restrict__ pos_W, const float* __restrict__ pos_b,
                       const float* __restrict__ edge_W, float* __restrict__ T) {
  int n = blockIdx.x / 66, dd = blockIdx.x % 66, c = threadIdx.x;
  float acc = 0.f;
#pragma unroll
  for (int m = 0; m < 16; m++)
    acc += (pos_W[dd * 16 + m] + pos_b[m]) * edge_W[(n * 16 + m) * EFn + c];
  T[(size_t)(n * 66 + dd) * EFn + c] = acc;
}

// ---------------- Kernel A: top-K + edge metadata + node features ----------------
__global__ __launch_bounds__(256) void pf_topk(
    const float* __restrict__ dist_ca, const float* __restrict__ mask_angle,
    const float* __restrict__ dihedral, const int* __restrict__ Sarr,
    const int* __restrict__ ridx, const int* __restrict__ chain,
    const float* __restrict__ embed_tab, const float* __restrict__ node_W,
    const float* __restrict__ node_b, const float* __restrict__ ln_n_g,
    const float* __restrict__ ln_n_b,
    uint2* __restrict__ ew, float* __restrict__ out) {
  __shared__ unsigned int s_hist[256];
  __shared__ unsigned int s_wtot[4];
  __shared__ unsigned long long s_cand[64];
  __shared__ unsigned long long s_w64[4];
  __shared__ float s_mx[4], s_mn2[4], s_mx2[4];
  __shared__ float s_v4[4];
  __shared__ int s_nidx[Kn];
  __shared__ float s_nval[Kn];
  __shared__ int s_bsel, s_tot, s_cnt;

  const int tid = threadIdx.x;
  const int lane = tid & 63, wid = tid >> 6;
  const int r = blockIdx.x;                    // row = b*L + i
  const int b = r >> 11;
  const size_t rowoff = (size_t)r * Ln;

  // element ownership: m<4 -> tid*4+m ; m>=4 -> 1024 + tid*4 + (m-4)
  const int j0 = tid << 2;

  // ---------- Phase 1: vector load row, D = mask*dist, row max ----------
  float Dv[8], Mv[8];
  {
    float4 da = *(const float4*)(dist_ca + rowoff + j0);
    float4 db = *(const float4*)(dist_ca + rowoff + 1024 + j0);
    float4 ma = *(const float4*)(mask_angle + rowoff + j0);
    float4 mb = *(const float4*)(mask_angle + rowoff + 1024 + j0);
    Mv[0] = ma.x; Mv[1] = ma.y; Mv[2] = ma.z; Mv[3] = ma.w;
    Mv[4] = mb.x; Mv[5] = mb.y; Mv[6] = mb.z; Mv[7] = mb.w;
    Dv[0] = ma.x * da.x; Dv[1] = ma.y * da.y; Dv[2] = ma.z * da.z; Dv[3] = ma.w * da.w;
    Dv[4] = mb.x * db.x; Dv[5] = mb.y * db.y; Dv[6] = mb.z * db.z; Dv[7] = mb.w * db.w;
  }
  float lmax = -3.4e38f;
#pragma unroll
  for (int m = 0; m < 8; m++) lmax = fmaxf(lmax, Dv[m]);
#pragma unroll
  for (int o = 32; o; o >>= 1) lmax = fmaxf(lmax, __shfl_xor(lmax, o));
  if (!lane) s_mx[wid] = lmax;
  if (!tid) s_cnt = 0;
  __syncthreads();
  const float Dmax = fmaxf(fmaxf(s_mx[0], s_mx[1]), fmaxf(s_mx[2], s_mx[3]));

  // ---------- Phase 2: adjust, min/max for bucketing ----------
  float lmin = 3.4e38f; lmax = -3.4e38f;
#pragma unroll
  for (int m = 0; m < 8; m++) {
    float adj = Dv[m] + (1.0f - Mv[m]) * Dmax;
    Dv[m] = adj;
    lmin = fminf(lmin, adj); lmax = fmaxf(lmax, adj);
  }
#pragma unroll
  for (int o = 32; o; o >>= 1) {
    lmin = fminf(lmin, __shfl_xor(lmin, o));
    lmax = fmaxf(lmax, __shfl_xor(lmax, o));
  }
  if (!lane) { s_mn2[wid] = lmin; s_mx2[wid] = lmax; }
  s_hist[tid] = 0u;
  __syncthreads();
  const float m0 = fminf(fminf(s_mn2[0], s_mn2[1]), fminf(s_mn2[2], s_mn2[3]));
  const float M0 = fmaxf(fmaxf(s_mx2[0], s_mx2[1]), fmaxf(s_mx2[2], s_mx2[3]));
  const float rng = M0 - m0;
  const float scale = (rng > 0.f) ? 255.0f / rng : 0.f;

  // ---------- Phase 3: bucket histogram ----------
  int binv[8];
#pragma unroll
  for (int m = 0; m < 8; m++) {
    int bin = (int)((Dv[m] - m0) * scale);
    bin = bin < 0 ? 0 : (bin > 255 ? 255 : bin);
    binv[m] = bin;
    atomicAdd(&s_hist[bin], 1u);
  }
  __syncthreads();

  // ---------- Phase 4: 1-barrier scan (wave shuffle + wave totals) ----------
  {
    const unsigned int orig = s_hist[tid];
    unsigned int v = orig;
#pragma unroll
    for (int o = 1; o < 64; o <<= 1) {
      unsigned int u = __shfl_up(v, o);
      if (lane >= o) v += u;
    }
    if (lane == 63) s_wtot[wid] = v;
    __syncthreads();
    unsigned int add = 0;
#pragma unroll
    for (int w = 0; w < 4; w++) if (w < wid) add += s_wtot[w];
    const unsigned int cum = v + add;
    if (cum >= (unsigned)Kn && (cum - orig) < (unsigned)Kn) {
      s_bsel = tid; s_tot = (int)cum;
    }
  }
  __syncthreads();
  const int bsel = s_bsel;
  const int tot = s_tot;

  // ---------- Phase 5: select K ----------
  if (tot <= 64) {
#pragma unroll
    for (int m = 0; m < 8; m++) {
      if (binv[m] <= bsel) {
        int p = atomicAdd(&s_cnt, 1);
        int j = (m < 4) ? (j0 + m) : (1024 + j0 + m - 4);
        s_cand[p] = ((unsigned long long)orderKey(Dv[m]) << 16) | (unsigned)j;
      }
    }
    __syncthreads();
    // 64-lane bitonic sort ascending — matches jax top_k tie-break (value, then lower idx)
    if (tid < 64) {
      unsigned long long v = (tid < tot) ? s_cand[tid] : ~0ull;
#pragma unroll
      for (int size = 2; size <= 64; size <<= 1) {
        for (int stride = size >> 1; stride > 0; stride >>= 1) {
          unsigned long long p = __shfl_xor(v, stride);
          bool keepMin = (((tid & stride) == 0) == ((tid & size) == 0));
          v = ((v < p) != keepMin) ? p : v;
        }
      }
      if (tid < Kn) {
        s_nidx[tid] = (int)(v & 0xffffull);
        s_nval[tid] = keyToFloat((unsigned int)(v >> 16));
      }
    }
  } else {
    // exact fallback: registers + validity mask (rare: degenerate rows)
    unsigned int valid = 0xffu;
    for (int t = 0; t < Kn; t++) {
      unsigned long long lm = ~0ull;
#pragma unroll
      for (int m = 0; m < 8; m++) {
        if (valid & (1u << m)) {
          int j = (m < 4) ? (j0 + m) : (1024 + j0 + m - 4);
          lm = u64min(lm, ((unsigned long long)orderKey(Dv[m]) << 16) | (unsigned)j);
        }
      }
#pragma unroll
      for (int o = 32; o; o >>= 1) lm = u64min(lm, __shfl_xor(lm, o));
      if (!lane) s_w64[wid] = lm;
      __syncthreads();
      unsigned long long g = u64min(u64min(s_w64[0], s_w64[1]), u64min(s_w64[2], s_w64[3]));
      int j = (int)(g & 0xffffull);
      int owner = (j < 1024) ? (j >> 2) : ((j - 1024) >> 2);
      if (tid == owner) valid &= ~(1u << ((j < 1024) ? (j & 3) : (4 + (j & 3))));
      if (!tid) { s_nidx[t] = j; s_nval[t] = keyToFloat((unsigned int)(g >> 16)); }
      __syncthreads();
    }
  }
  __syncthreads();

  // ---------- Phase 6: E_idx + packed edge metadata ----------
  if (tid < Kn) {
    int j = s_nidx[tid];
    out[IDX_OFF + (size_t)r * Kn + tid] = (float)j;
    int rj = ridx[(size_t)b * Ln + j];
    int sc = (chain[r] == chain[(size_t)b * Ln + j]) ? 1 : 0;
    int d0 = (ridx[r] - rj) + 32;
    d0 = d0 < 0 ? 0 : (d0 > 64 ? 64 : d0);
    d0 = sc ? d0 : 65;
    unsigned int meta = (unsigned)j | ((unsigned)d0 << 11) | ((unsigned)sc << 18);
    ew[(size_t)r * Kn + tid] = make_uint2(meta, __float_as_uint(s_nval[tid]));
  }

  // ---------- Phase 7: node features V ----------
  float a = 0.f;
  if (tid < EFn) {
    const int sv = Sarr[r];
    a = node_b[tid];
#pragma unroll
    for (int m = 0; m < 6; m++) a = fmaf(embed_tab[sv * 6 + m], node_W[m * EFn + tid], a);
#pragma unroll
    for (int m = 0; m < 6; m++) a = fmaf(dihedral[(size_t)r * 6 + m], node_W[(6 + m) * EFn + tid], a);
    float s1 = a, s2 = a * a;
#pragma unroll
    for (int o = 32; o; o >>= 1) { s1 += __shfl_xor(s1, o); s2 += __shfl_xor(s2, o); }
    if (!lane) { s_v4[wid * 2] = s1; s_v4[wid * 2 + 1] = s2; }
  }
  __syncthreads();
  if (tid < EFn) {
    const float S1 = s_v4[0] + s_v4[2], S2 = s_v4[1] + s_v4[3];
    const float mean = S1 * (1.0f / 128.0f);
    float var = S2 * (1.0f / 128.0f) - mean * mean;
    var = fmaxf(var, 0.f);
    const float inv = rsqrtf(var + 1e-5f);
    out[(size_t)r * EFn + tid] = (a - mean) * inv * ln_n_g[tid] + ln_n_b[tid];
  }
}

// ---------------- Kernel B: edge features (no LDS, no barriers) ----------------
// 8 threads per edge x 16 channels each; block = 32 edges.
__global__ __launch_bounds__(256) void pf_edge(
    const uint2* __restrict__ ew, const float* __restrict__ omega,
    const float* __restrict__ theta, const float* __restrict__ phi,
    const float* __restrict__ T, const float* __restrict__ edge_W,
    const float* __restrict__ ln_e_g, const float* __restrict__ ln_e_b,
    float* __restrict__ out) {
  const int tid = threadIdx.x;
  const int e = blockIdx.x * 32 + (tid >> 3);
  const int sub = tid & 7, c0 = sub << 4;

  const uint2 md = ew[e];
  const unsigned meta = md.x;
  const float dval = __uint_as_float(md.y);
  const int j = meta & 0x7ff;
  const int d0 = (meta >> 11) & 0x7f;
  const int sc = (meta >> 18) & 1;
  const int r = e >> 5;

  // gather trig inputs: lanes 0..2 of each 8-lane group load omega/theta/phi
  const size_t pij = (size_t)r * Ln + j;
  float ang = 0.f;
  if (sub == 0) ang = omega[pij];
  else if (sub == 1) ang = theta[pij];
  else if (sub == 2) ang = phi[pij];
  const float cv = cosf(ang), sv = sinf(ang);
  const int base = (tid & 63) & ~7;
  float tr[6];
  tr[0] = __shfl(cv, base + 0); tr[1] = __shfl(sv, base + 0);
  tr[2] = __shfl(cv, base + 1); tr[3] = __shfl(sv, base + 1);
  tr[4] = __shfl(cv, base + 2); tr[5] = __shfl(sv, base + 2);

  float acc[16];
  {
    const float* Tp = T + (size_t)d0 * EFn + c0;
#pragma unroll
    for (int m = 0; m < 16; m++) acc[m] = Tp[m];
  }
#pragma unroll
  for (int n = 1; n < 7; n++) {
    int ee = (int)tr[n - 1];                  // trunc toward zero (torch .long())
    int d = ee + 32; d = d < 0 ? 0 : (d > 64 ? 64 : d);
    d = sc ? d : 65;
    const float* Tp = T + (size_t)(n * 66 + d) * EFn + c0;
#pragma unroll
    for (int m = 0; m < 16; m++) acc[m] += Tp[m];
  }
#pragma unroll
  for (int rr = 0; rr < 16; rr++) {
    float mu = 2.0f + (20.0f / 15.0f) * (float)rr;
    float t = (dval - mu) * 0.8f;             // 1/1.25
    float rb = __expf(-t * t);
    const float* W2 = edge_W + (size_t)(112 + rr) * EFn + c0;
#pragma unroll
    for (int m = 0; m < 16; m++) acc[m] = fmaf(rb, W2[m], acc[m]);
  }
  // LayerNorm over 128 channels = 8 consecutive lanes
  float s1 = 0.f, s2 = 0.f;
#pragma unroll
  for (int m = 0; m < 16; m++) { s1 += acc[m]; s2 += acc[m] * acc[m]; }
#pragma unroll
  for (int o = 1; o < 8; o <<= 1) { s1 += __shfl_xor(s1, o); s2 += __shfl_xor(s2, o); }
  const float mean = s1 * (1.0f / 128.0f);
  float var = s2 * (1.0f / 128.0f) - mean * mean;
  var = fmaxf(var, 0.f);
  const float inv = rsqrtf(var + 1e-5f);
  float y[16];
#pragma unroll
  for (int m = 0; m < 16; m++)
    y[m] = (acc[m] - mean) * inv * ln_e_g[c0 + m] + ln_e_b[c0 + m];
  float4* dst = (float4*)(out + V_ELEMS + ((size_t)e * EFn + c0));
  dst[0] = make_float4(y[0],  y[1],  y[2],  y[3]);
  dst[1] = make_float4(y[4],  y[5],  y[6],  y[7]);
  dst[2] = make_float4(y[8],  y[9],  y[10], y[11]);
  dst[3] = make_float4(y[12], y[13], y[14], y[15]);
}

extern "C" void kernel_launch(void* const* d_in, const int* in_sizes, int n_in,
                              void* d_out, int out_size, void* d_ws, size_t ws_size,
                              hipStream_t stream) {
  (void)in_sizes; (void)n_in; (void)out_size; (void)ws_size;
  const float* dist_ca    = (const float*)d_in[0];
  const float* omega      = (const float*)d_in[1];
  const float* theta      = (const float*)d_in[2];
  const float* phi        = (const float*)d_in[3];
  const float* dihedral   = (const float*)d_in[4];
  const float* mask_angle = (const float*)d_in[5];
  // d_in[6] = mask (unused by reference)
  const int*   S          = (const int*)d_in[7];
  const int*   ridx       = (const int*)d_in[8];
  const int*   chain      = (const int*)d_in[9];
  const float* pos_W      = (const float*)d_in[10];
  const float* pos_b      = (const float*)d_in[11];
  const float* edge_W     = (const float*)d_in[12];
  const float* ln_e_g     = (const float*)d_in[13];
  const float* ln_e_b     = (const float*)d_in[14];
  const float* embed_tab  = (const float*)d_in[15];
  const float* node_W     = (const float*)d_in[16];
  const float* node_b     = (const float*)d_in[17];
  const float* ln_n_g     = (const float*)d_in[18];
  const float* ln_n_b     = (const float*)d_in[19];

  float* T  = (float*)d_ws;                                  // 236,544 B
  uint2* ew = (uint2*)((char*)d_ws + T_BYTES);               // 262,144 * 8 B

  pf_tab<<<7 * 66, 128, 0, stream>>>(pos_W, pos_b, edge_W, T);
  pf_topk<<<ROWS, 256, 0, stream>>>(dist_ca, mask_angle, dihedral, S, ridx, chain,
                                    embed_tab, node_W, node_b, ln_n_g, ln_n_b,
                                    ew, (float*)d_out);
  pf_edge<<<ROWS * Kn / 32, 256, 0, stream>>>(ew, omega, theta, phi, T, edge_W,
                                              ln_e_g, ln_e_b, (float*)d_out);
}